// Round 16
// baseline (757.239 us; speedup 1.0000x reference)
//
#include <hip/hip_runtime.h>
#include <hip/hip_bf16.h>
#include <cstdio>

typedef short s16x8 __attribute__((ext_vector_type(8)));
typedef unsigned short u16x8 __attribute__((ext_vector_type(8)));
typedef float f32x4 __attribute__((ext_vector_type(4)));

#define B_TOK 8192      // b*l
#define DDIM 1024
#define INTER 2816
#define NEXP 8
#define CAP_TILES 136               // max sum ceil(cnt[e]/128) = 135; capacity 136
#define CAP_SLOTS (CAP_TILES * 128) // 17408
#define NWG1 (CAP_TILES * (INTER / 256))  // 1496 = 8 * 187
#define NWG2 (CAP_TILES * (DDIM / 128))   // 1088 = 8 * 136

__device__ __forceinline__ unsigned short f2bf(float f) {
    unsigned int u = __float_as_uint(f);
    unsigned int r = u + 0x7fffu + ((u >> 16) & 1u);
    return (unsigned short)(r >> 16);
}

__device__ __forceinline__ float bf2f(unsigned short u) {
    unsigned int x = ((unsigned int)u) << 16;
    return __uint_as_float(x);
}

__device__ __forceinline__ void gload_lds16(const void* g, void* l) {
    __builtin_amdgcn_global_load_lds(
        (const __attribute__((address_space(1))) unsigned int*)g,
        (__attribute__((address_space(3))) unsigned int*)l, 16, 0, 0);
}

// ---------------- transpose+convert ----------------
__global__ __launch_bounds__(256) void transpose_convert_v2(
    const float* __restrict__ src, unsigned short* __restrict__ dst,
    int K, int N) {
    __shared__ unsigned short tile[64][70];
    int e = blockIdx.z;
    src += (size_t)e * K * N;
    dst += (size_t)e * K * N;
    int n0 = blockIdx.x * 64, k0 = blockIdx.y * 64;
    int t = threadIdx.x;
    int lr = t >> 4;          // 0..15
    int lc = (t & 15) * 4;    // 0..60
#pragma unroll
    for (int p = 0; p < 4; ++p) {
        int kl = p * 16 + lr;
        float4 v = *(const float4*)(src + (size_t)(k0 + kl) * N + n0 + lc);
        tile[kl][lc + 0] = f2bf(v.x);
        tile[kl][lc + 1] = f2bf(v.y);
        tile[kl][lc + 2] = f2bf(v.z);
        tile[kl][lc + 3] = f2bf(v.w);
    }
    __syncthreads();
    int sn = t >> 3;          // 0..31
    int sk = (t & 7) * 8;     // 0..56
#pragma unroll
    for (int p = 0; p < 2; ++p) {
        int nl = p * 32 + sn;
        u16x8 o;
#pragma unroll
        for (int j = 0; j < 8; ++j) o[j] = tile[sk + j][nl];
        *(u16x8*)(dst + (size_t)(n0 + nl) * K + k0 + sk) = o;
    }
}

// ---------------- gating v3: 512 blocks, LDS-aggregated counts/sums ----------
__global__ __launch_bounds__(256) void gating_kernel(
    const float* __restrict__ h,
    const float* __restrict__ gw,
    float* __restrict__ route,
    int* __restrict__ sel01,
    float2* __restrict__ wpair,
    int* __restrict__ counts,
    float* __restrict__ sums,
    unsigned short* __restrict__ hb) {
    __shared__ int lcnt[8];
    __shared__ float lsum[8];
    const int tid = threadIdx.x;
    if (tid < 8) { lcnt[tid] = 0; lsum[tid] = 0.f; }
    __syncthreads();
    const int wid = tid >> 6, lane = tid & 63;

    for (int t0 = 0; t0 < B_TOK; t0 += 2048) {
        int t = t0 + blockIdx.x * 4 + wid;
        const float* hp = h + (size_t)t * DDIM + lane * 16;
        float4 hv[4];
#pragma unroll
        for (int p = 0; p < 4; ++p) hv[p] = ((const float4*)hp)[p];

        u16x8 o0, o1;
        o0[0] = f2bf(hv[0].x); o0[1] = f2bf(hv[0].y); o0[2] = f2bf(hv[0].z); o0[3] = f2bf(hv[0].w);
        o0[4] = f2bf(hv[1].x); o0[5] = f2bf(hv[1].y); o0[6] = f2bf(hv[1].z); o0[7] = f2bf(hv[1].w);
        o1[0] = f2bf(hv[2].x); o1[1] = f2bf(hv[2].y); o1[2] = f2bf(hv[2].z); o1[3] = f2bf(hv[2].w);
        o1[4] = f2bf(hv[3].x); o1[5] = f2bf(hv[3].y); o1[6] = f2bf(hv[3].z); o1[7] = f2bf(hv[3].w);
        unsigned short* hbp = hb + (size_t)t * DDIM + lane * 16;
        *(u16x8*)hbp = o0;
        *(u16x8*)(hbp + 8) = o1;

        const float4* gp4 = (const float4*)(gw + (size_t)lane * 16 * NEXP);
        float s[8] = {0, 0, 0, 0, 0, 0, 0, 0};
#pragma unroll
        for (int p = 0; p < 4; ++p) {
#pragma unroll
            for (int q = 0; q < 4; ++q) {
                int kk = p * 4 + q;
                float hvk = (q == 0) ? hv[p].x : (q == 1) ? hv[p].y : (q == 2) ? hv[p].z : hv[p].w;
                float4 a = gp4[kk * 2], b = gp4[kk * 2 + 1];
                s[0] += hvk * a.x; s[1] += hvk * a.y; s[2] += hvk * a.z; s[3] += hvk * a.w;
                s[4] += hvk * b.x; s[5] += hvk * b.y; s[6] += hvk * b.z; s[7] += hvk * b.w;
            }
        }
#pragma unroll
        for (int off = 32; off > 0; off >>= 1) {
#pragma unroll
            for (int e = 0; e < 8; ++e) s[e] += __shfl_down(s[e], off);
        }
        if (lane == 0) {
            float m0 = -1e30f; int i0 = 0;
#pragma unroll
            for (int e = 0; e < 8; ++e) if (s[e] > m0) { m0 = s[e]; i0 = e; }
            float m1 = -1e30f; int i1 = -1;
#pragma unroll
            for (int e = 0; e < 8; ++e) if (e != i0 && s[e] > m1) { m1 = s[e]; i1 = e; }
            float d = __expf(m1 - m0);
            float w0 = 1.f / (1.f + d);
            float w1 = d * w0;
#pragma unroll
            for (int e = 0; e < 8; ++e)
                route[(size_t)t * 8 + e] = (e == i0) ? w0 : ((e == i1) ? w1 : 0.f);
            sel01[t] = i0 | (i1 << 8);
            wpair[t] = make_float2(w0, w1);
            atomicAdd(&lcnt[i0], 1);
            atomicAdd(&lcnt[i1], 1);
            atomicAdd(&lsum[i0], w0);
            atomicAdd(&lsum[i1], w1);
        }
    }
    __syncthreads();
    if (tid < 8) {
        atomicAdd(&counts[tid], lcnt[tid]);
        atomicAdd(&sums[tid], lsum[tid]);
    }
}

// single block: per-expert 128-aligned slot offsets + tile table + lb_loss finalize
__global__ void setup_kernel(const int* __restrict__ counts,
                             const float* __restrict__ sums,
                             int* __restrict__ aoff,
                             int* __restrict__ tile_e,
                             int* __restrict__ tile_s0,
                             float* __restrict__ lb) {
    __shared__ int s_aoff[8], s_t0[9];
    if (threadIdx.x == 0) {
        int acc_slot = 0, acc_tile = 0;
        for (int e = 0; e < 8; ++e) {
            s_aoff[e] = acc_slot;
            s_t0[e] = acc_tile;
            int nt = (counts[e] + 127) >> 7;
            acc_slot += nt << 7;
            acc_tile += nt;
        }
        s_t0[8] = acc_tile;
        for (int e = 0; e < 8; ++e) aoff[e] = s_aoff[e];
        float acc = 0.f;
        for (int e = 0; e < 8; ++e) {
            float p = sums[e] / (float)B_TOK;
            acc += p * p;
        }
        lb[0] = 0.01f * acc;
    }
    __syncthreads();
    int t = threadIdx.x;
    if (t < CAP_TILES) {
        int e = -1, s0 = 0;
        for (int x = 0; x < 8; ++x)
            if (t >= s_t0[x] && t < s_t0[x + 1]) { e = x; s0 = s_aoff[x] + ((t - s_t0[x]) << 7); }
        tile_e[t] = e;
        tile_s0[t] = s0;
    }
}

// fill v2: per-block LDS ranks + one block-reservation atomic per expert.
__global__ __launch_bounds__(256) void fill_kernel(
    const int* __restrict__ sel01,
    const int* __restrict__ aoff,
    int* __restrict__ rank,
    int* __restrict__ idx,
    int2* __restrict__ tslot) {
    __shared__ int lcnt[8], lbase[8];
    const int tid = threadIdx.x;
    if (tid < 8) lcnt[tid] = 0;
    __syncthreads();
    int t = blockIdx.x * 256 + tid;
    int s = sel01[t];
    int e0 = s & 0xff, e1 = (s >> 8) & 0xff;
    int lr0 = atomicAdd(&lcnt[e0], 1);
    int lr1 = atomicAdd(&lcnt[e1], 1);
    __syncthreads();
    if (tid < 8) lbase[tid] = atomicAdd(&rank[tid], lcnt[tid]);
    __syncthreads();
    int sl0 = aoff[e0] + lbase[e0] + lr0;
    int sl1 = aoff[e1] + lbase[e1] + lr1;
    idx[sl0] = t;
    idx[sl1] = t;
    tslot[t] = make_int2(sl0, sl1);
}

// ---------------- GEMM1 4-phase: merged G+U (32 MFMA per barrier-pair) --------
// 128 rows x 256 cols, dual G/U, BK=64, 512 thr (8 waves 2r x 4c). LDS 160KiB.
// Period = 2 K-tiles, 4 phases: {slot0 kk0, slot0 kk1, slot1 kk0, slot1 kk1},
// each phase reads A+G+U frags (12 ds_read_b128) and runs 32 MFMA.
// Staging ring (10 gloads/K-tile): ph0 stages slot1-rest[6] (vmcnt(10));
// ph1 stages slot0 A+G0[4]; ph2 stages slot0-rest[6] (vmcnt(10), last: 0);
// ph3 stages slot1 A+G0[4]. Prologue: slot0 full + slot1 A+G0, vmcnt(4).
// Per-accumulator K-order identical to r14/r15 -> bitwise-identical act.
__global__ __launch_bounds__(512, 2) void gemm1_4ph(
    const unsigned short* __restrict__ A,
    const unsigned short* __restrict__ Bg,
    const unsigned short* __restrict__ Bu,
    const int* __restrict__ tile_e,
    const int* __restrict__ tile_s0,
    const int* __restrict__ idx,
    unsigned short* __restrict__ act) {
    const int lin = blockIdx.x;
    const int swz = (lin & 7) * (NWG1 / 8) + (lin >> 3);
    const int tileId = swz % CAP_TILES;
    const int colBase = (swz / CAP_TILES) * 256;
    int e = tile_e[tileId];
    if (e < 0) return;
    const int slot0 = tile_s0[tileId];
    const unsigned short* Gp = Bg + (size_t)e * DDIM * INTER;
    const unsigned short* Up = Bu + (size_t)e * DDIM * INTER;

    __shared__ unsigned short lds[81920];   // 160 KiB

    const int t = threadIdx.x;
    const int w = t >> 6, lane = t & 63;
    const int wr = w >> 2, wc = w & 3;
    const int l15 = lane & 15;
    const int kb8 = (lane >> 4) * 8;
    const int t8 = t * 8;
    const int rowIdx = t >> 3;                                  // 0..63
    const int kus = ((t & 7) * 8) ^ (((t >> 3) & 7) << 3);      // swizzled src col

    const unsigned short* Ab0 = A + (size_t)idx[slot0 + rowIdx] * DDIM + kus;
    const unsigned short* Ab1 = A + (size_t)idx[slot0 + 64 + rowIdx] * DDIM + kus;
    const unsigned int gbase = (unsigned int)(colBase + rowIdx) * DDIM + kus;

    f32x4 accG[4][4], accU[4][4];
#pragma unroll
    for (int i = 0; i < 4; ++i)
#pragma unroll
        for (int jq = 0; jq < 4; ++jq) { accG[i][jq] = (f32x4)(0.f); accU[i][jq] = (f32x4)(0.f); }

#define STA(s, kt) { \
    gload_lds16(Ab0 + (kt) * 64, (void*)(lds + (s) * 40960 + t8)); \
    gload_lds16(Ab1 + (kt) * 64, (void*)(lds + (s) * 40960 + 4096 + t8)); }
#define STG(s, hh, kt) { \
    gload_lds16(Gp + gbase + (2 * (hh)) * 65536 + (kt) * 64,     (void*)(lds + (s) * 40960 + 8192 + (2 * (hh)) * 4096 + t8)); \
    gload_lds16(Gp + gbase + (2 * (hh) + 1) * 65536 + (kt) * 64, (void*)(lds + (s) * 40960 + 8192 + (2 * (hh) + 1) * 4096 + t8)); }
#define STU(s, hh, kt) { \
    gload_lds16(Up + gbase + (2 * (hh)) * 65536 + (kt) * 64,     (void*)(lds + (s) * 40960 + 24576 + (2 * (hh)) * 4096 + t8)); \
    gload_lds16(Up + gbase + (2 * (hh) + 1) * 65536 + (kt) * 64, (void*)(lds + (s) * 40960 + 24576 + (2 * (hh) + 1) * 4096 + t8)); }
#define DSA(s, kk) { _Pragma("unroll") for (int mf = 0; mf < 4; ++mf) { \
    int lr = wr * 64 + mf * 16 + l15; \
    a[mf] = *(const s16x8*)&lds[(s) * 40960 + lr * 64 + (((kk) * 32 + kb8) ^ ((lr & 7) << 3))]; } }
#define DSB(dst, s, off, kk) { _Pragma("unroll") for (int nf = 0; nf < 4; ++nf) { \
    int rr = wc * 64 + nf * 16 + l15; \
    dst[nf] = *(const s16x8*)&lds[(s) * 40960 + (off) + rr * 64 + (((kk) * 32 + kb8) ^ ((rr & 7) << 3))]; } }
#define MM(ACC, B) { _Pragma("unroll") for (int mf = 0; mf < 4; ++mf) \
    _Pragma("unroll") for (int nf = 0; nf < 4; ++nf) \
        ACC[mf][nf] = __builtin_amdgcn_mfma_f32_16x16x32_bf16(a[mf], B[nf], ACC[mf][nf], 0, 0, 0); }
#define PH_TAIL2 \
    __builtin_amdgcn_s_barrier(); \
    asm volatile("s_waitcnt lgkmcnt(0)" ::: "memory"); \
    __builtin_amdgcn_sched_barrier(0); \
    __builtin_amdgcn_s_setprio(1); \
    MM(accG, bg); \
    MM(accU, bu); \
    __builtin_amdgcn_s_setprio(0); \
    __builtin_amdgcn_sched_barrier(0); \
    __builtin_amdgcn_s_barrier();

    // prologue: slot0 <- tile0 (10 loads), slot1 A+Gh0 <- tile1 (4 loads)
    STA(0, 0); STG(0, 0, 0); STG(0, 1, 0); STU(0, 0, 0); STU(0, 1, 0);
    STA(1, 1); STG(1, 0, 1);
    asm volatile("s_waitcnt vmcnt(4)" ::: "memory");
    __builtin_amdgcn_s_barrier();

    s16x8 a[4], bg[4], bu[4];
#pragma unroll 1
    for (int j = 0; j < 8; ++j) {   // DDIM/64/2 = 8 periods
        const bool nl = (j < 7);
        const int t1 = 2 * j + 1, t2 = 2 * j + 2, t3 = 2 * j + 3;
        // ph0: slot0 kk0 (G+U); stage slot1 rest (Gh1,Uh0,Uh1 of t1)
        DSA(0, 0); DSB(bg, 0, 8192, 0); DSB(bu, 0, 24576, 0);
        STG(1, 1, t1); STU(1, 0, t1); STU(1, 1, t1);
        asm volatile("s_waitcnt vmcnt(10)" ::: "memory");
        PH_TAIL2;
        // ph1: slot0 kk1; stage slot0 A+Gh0 (t2)
        DSA(0, 1); DSB(bg, 0, 8192, 1); DSB(bu, 0, 24576, 1);
        if (nl) { STA(0, t2); STG(0, 0, t2); }
        PH_TAIL2;
        // ph2: slot1 kk0; stage slot0 rest (t2)
        DSA(1, 0); DSB(bg, 1, 8192, 0); DSB(bu, 1, 24576, 0);
        if (nl) { STG(0, 1, t2); STU(0, 0, t2); STU(0, 1, t2); }
        if (nl) { asm volatile("s_waitcnt vmcnt(10)" ::: "memory"); }
        else    { asm volatile("s_waitcnt vmcnt(0)" ::: "memory"); }
        PH_TAIL2;
        // ph3: slot1 kk1; stage slot1 A+Gh0 (t3)
        DSA(1, 1); DSB(bg, 1, 8192, 1); DSB(bu, 1, 24576, 1);
        if (nl) { STA(1, t3); STG(1, 0, t3); }
        PH_TAIL2;
    }

#pragma unroll
    for (int mf = 0; mf < 4; ++mf)
#pragma unroll
        for (int nf = 0; nf < 4; ++nf)
#pragma unroll
            for (int jq = 0; jq < 4; ++jq) {
                int r = slot0 + wr * 64 + mf * 16 + (lane >> 4) * 4 + jq;
                int c = colBase + wc * 64 + nf * 16 + l15;
                float g = accG[mf][nf][jq], u = accU[mf][nf][jq];
                float sg = 1.f / (1.f + __expf(-g));
                act[(size_t)r * INTER + c] = f2bf(g * sg * u);
            }
#undef STA
#undef STG
#undef STU
#undef DSA
#undef DSB
#undef MM
#undef PH_TAIL2
}

// ---------------- GEMM2 v4 + XCD-bijective swizzle; 4 blocks/CU ---------------
__global__ __launch_bounds__(256, 4) void gemm2_sparse_v4(
    const unsigned short* __restrict__ A,
    const unsigned short* __restrict__ Bd,
    const int* __restrict__ tile_e,
    const int* __restrict__ tile_s0,
    unsigned short* __restrict__ y) {
    const int lin = blockIdx.x;
    const int swz = (lin & 7) * (NWG2 / 8) + (lin >> 3);
    const int tileId = swz % CAP_TILES;
    const int colBase = (swz / CAP_TILES) * 128;
    int e = tile_e[tileId];
    if (e < 0) return;
    const int slot0 = tile_s0[tileId];
    Bd += (size_t)e * DDIM * INTER;

    __shared__ unsigned short sA[2][128 * 32];
    __shared__ unsigned short sB[2][128 * 32];
    const int tid = threadIdx.x, wid = tid >> 6, lane = tid & 63;
    const int wr = wid >> 1, wc = wid & 1;

    f32x4 acc[4][4];
#pragma unroll
    for (int i = 0; i < 4; ++i)
#pragma unroll
        for (int j = 0; j < 4; ++j) acc[i][j] = (f32x4)(0.f);

    const int c0 = wid, c1 = wid + 4;
    const int srow = lane >> 2;
    const int skoff = (lane & 3) * 8;
    const int rA = (lane & 15) * 32 + (lane >> 4) * 8;

    const size_t gA0 = (size_t)(slot0 + c0 * 16 + srow) * INTER + skoff;
    const size_t gA1 = (size_t)(slot0 + c1 * 16 + srow) * INTER + skoff;
    const size_t gB0 = (size_t)(colBase + c0 * 16 + srow) * INTER + skoff;
    const size_t gB1 = (size_t)(colBase + c1 * 16 + srow) * INTER + skoff;

    for (int k0 = 0; k0 < INTER; k0 += 64) {
#pragma unroll
        for (int kk = 0; kk < 2; ++kk) {
            int k = k0 + kk * 32;
            gload_lds16(A + gA0 + k, sA[kk] + c0 * 512);
            gload_lds16(A + gA1 + k, sA[kk] + c1 * 512);
            gload_lds16(Bd + gB0 + k, sB[kk] + c0 * 512);
            gload_lds16(Bd + gB1 + k, sB[kk] + c1 * 512);
        }
        asm volatile("s_waitcnt vmcnt(0)" ::: "memory");
        __syncthreads();

#pragma unroll
        for (int kk = 0; kk < 2; ++kk) {
            s16x8 a[4], b[4];
#pragma unroll
            for (int mf = 0; mf < 4; ++mf)
                a[mf] = *(const s16x8*)&sA[kk][(wr * 64 + mf * 16) * 32 + rA];
#pragma unroll
            for (int nf = 0; nf < 4; ++nf)
                b[nf] = *(const s16x8*)&sB[kk][(wc * 64 + nf * 16) * 32 + rA];
#pragma unroll
            for (int mf = 0; mf < 4; ++mf)
#pragma unroll
                for (int nf = 0; nf < 4; ++nf)
                    acc[mf][nf] = __builtin_amdgcn_mfma_f32_16x16x32_bf16(a[mf], b[nf], acc[mf][nf], 0, 0, 0);
        }
        __syncthreads();
    }

#pragma unroll
    for (int mf = 0; mf < 4; ++mf)
#pragma unroll
        for (int j = 0; j < 4; ++j) {
            int slot = slot0 + wr * 64 + mf * 16 + (lane >> 4) * 4 + j;
#pragma unroll
            for (int nf = 0; nf < 4; ++nf) {
                int c = colBase + wc * 64 + nf * 16 + (lane & 15);
                y[(size_t)slot * DDIM + c] = f2bf(acc[mf][nf][j]);
            }
        }
}

// out[t][c] = w0 * y[sl0][c] + w1 * y[sl1][c]; y is bf16, out f32
__global__ __launch_bounds__(256) void combine_kernel(
    const unsigned short* __restrict__ y,
    const int2* __restrict__ tslot,
    const float2* __restrict__ wpair,
    float* __restrict__ out) {
    int gid = blockIdx.x * 256 + threadIdx.x;  // 0 .. 8192*128-1
    int tok = gid >> 7;
    int c8 = (gid & 127) * 8;
    int2 ts = tslot[tok];
    float2 w = wpair[tok];
    u16x8 a = *(const u16x8*)(y + (size_t)ts.x * DDIM + c8);
    u16x8 b = *(const u16x8*)(y + (size_t)ts.y * DDIM + c8);
    float4 r0, r1;
    r0.x = w.x * bf2f(a[0]) + w.y * bf2f(b[0]);
    r0.y = w.x * bf2f(a[1]) + w.y * bf2f(b[1]);
    r0.z = w.x * bf2f(a[2]) + w.y * bf2f(b[2]);
    r0.w = w.x * bf2f(a[3]) + w.y * bf2f(b[3]);
    r1.x = w.x * bf2f(a[4]) + w.y * bf2f(b[4]);
    r1.y = w.x * bf2f(a[5]) + w.y * bf2f(b[5]);
    r1.z = w.x * bf2f(a[6]) + w.y * bf2f(b[6]);
    r1.w = w.x * bf2f(a[7]) + w.y * bf2f(b[7]);
    float* op = out + (size_t)tok * DDIM + c8;
    *(float4*)op = r0;
    *(float4*)(op + 4) = r1;
}

// ---------------- host ----------------

extern "C" void kernel_launch(void* const* d_in, const int* in_sizes, int n_in,
                              void* d_out, int out_size, void* d_ws, size_t ws_size,
                              hipStream_t stream) {
    const float* h = (const float*)d_in[0];
    const float* gate_w = (const float*)d_in[1];
    const float* wg = (const float*)d_in[2];
    const float* wu = (const float*)d_in[3];
    const float* wd = (const float*)d_in[4];

    float* out = (float*)d_out;                       // results: 8192*1024
    float* lb = out + (size_t)B_TOK * DDIM;           // 1
    float* route = lb + 1;                            // 8192*8

    const size_t SZ_META = 1 << 20;                           // 1 MiB
    const size_t SZ_HB = (size_t)B_TOK * DDIM * 2;            // 16,777,216
    const size_t SZ_W = (size_t)NEXP * DDIM * INTER * 2;      // 46,137,344 per tensor
    const size_t SZ_ACT = (size_t)CAP_SLOTS * INTER * 2;      // 98,041,856
    const size_t NEED = SZ_META + SZ_HB + 2 * SZ_W + SZ_ACT;  // ~198.5 MiB
    if (ws_size < NEED) {
        fprintf(stderr, "kernel_launch: ws too small: %zu < %zu\n", ws_size, NEED);
        return;
    }
    char* ws = (char*)d_ws;
    // meta layout (within first 1 MiB)
    int* counts = (int*)(ws + 0);            // 8
    int* rank = (int*)(ws + 32);             // 8
    int* aoff = (int*)(ws + 64);             // 8
    float* sums = (float*)(ws + 96);         // 8
    int* tile_e = (int*)(ws + 128);          // 136
    int* tile_s0 = (int*)(ws + 1024);        // 136
    int* sel01 = (int*)(ws + 2048);          // 8192
    float2* wpair = (float2*)(ws + 34816);   // 8192
    int* idx = (int*)(ws + 100352);          // 17408
    int2* tslot = (int2*)(ws + 262144);      // 8192 int2 = 64KB

    unsigned short* hb = (unsigned short*)(ws + SZ_META);
    unsigned short* wgT = (unsigned short*)(ws + SZ_META + SZ_HB);
    unsigned short* wuT = (unsigned short*)(ws + SZ_META + SZ_HB + SZ_W);
    unsigned short* act = (unsigned short*)(ws + SZ_META + SZ_HB + 2 * SZ_W);
    unsigned short* wdT = wgT;                               // reuse wgT space AFTER gemm1
    unsigned short* y = wuT;                                 // reuse wuT space AFTER gemm1 (35.6MB < 44MB)

    hipMemsetAsync(ws, 0, SZ_META, stream);

    transpose_convert_v2<<<dim3(INTER / 64, DDIM / 64, NEXP), 256, 0, stream>>>(wg, wgT, DDIM, INTER);
    transpose_convert_v2<<<dim3(INTER / 64, DDIM / 64, NEXP), 256, 0, stream>>>(wu, wuT, DDIM, INTER);

    gating_kernel<<<512, 256, 0, stream>>>(h, gate_w, route, sel01, wpair, counts, sums, hb);
    setup_kernel<<<1, 256, 0, stream>>>(counts, sums, aoff, tile_e, tile_s0, lb);
    fill_kernel<<<B_TOK / 256, 256, 0, stream>>>(sel01, aoff, rank, idx, tslot);

    gemm1_4ph<<<NWG1, 512, 0, stream>>>(hb, wgT, wuT, tile_e, tile_s0, idx, act);

    // now wgT/wuT are dead: transpose wd into wgT's space; y reuses wuT's space
    transpose_convert_v2<<<dim3(DDIM / 64, INTER / 64, NEXP), 256, 0, stream>>>(wd, wdT, INTER, DDIM);

    gemm2_sparse_v4<<<NWG2, 256, 0, stream>>>(act, wdT, tile_e, tile_s0, y);

    combine_kernel<<<(B_TOK * 128) / 256, 256, 0, stream>>>(y, tslot, wpair, out);
}

// Round 17
// 497.468 us; speedup vs baseline: 1.5222x; 1.5222x over previous
//
#include <hip/hip_runtime.h>
#include <hip/hip_bf16.h>
#include <cstdio>

typedef short s16x8 __attribute__((ext_vector_type(8)));
typedef unsigned short u16x8 __attribute__((ext_vector_type(8)));
typedef float f32x4 __attribute__((ext_vector_type(4)));

#define B_TOK 8192      // b*l
#define DDIM 1024
#define INTER 2816
#define NEXP 8
#define CAP_TILES 136               // max sum ceil(cnt[e]/128) = 135; capacity 136
#define CAP_SLOTS (CAP_TILES * 128) // 17408
#define NWG1 (CAP_TILES * (INTER / 256))  // 1496 = 8 * 187
#define NWG2 (CAP_TILES * (DDIM / 128))   // 1088 = 8 * 136

__device__ __forceinline__ unsigned short f2bf(float f) {
    unsigned int u = __float_as_uint(f);
    unsigned int r = u + 0x7fffu + ((u >> 16) & 1u);
    return (unsigned short)(r >> 16);
}

__device__ __forceinline__ float bf2f(unsigned short u) {
    unsigned int x = ((unsigned int)u) << 16;
    return __uint_as_float(x);
}

__device__ __forceinline__ void gload_lds16(const void* g, void* l) {
    __builtin_amdgcn_global_load_lds(
        (const __attribute__((address_space(1))) unsigned int*)g,
        (__attribute__((address_space(3))) unsigned int*)l, 16, 0, 0);
}

// ---------------- transpose+convert (fused wg+wu via z in [0,16)) -------------
__global__ __launch_bounds__(256) void transpose_convert_v2(
    const float* __restrict__ src0, const float* __restrict__ src1,
    unsigned short* __restrict__ dst0, unsigned short* __restrict__ dst1,
    int K, int N, int nz0) {
    __shared__ unsigned short tile[64][70];
    int z = blockIdx.z;
    const float* src = (z < nz0) ? src0 : src1;
    unsigned short* dst = (z < nz0) ? dst0 : dst1;
    int e = (z < nz0) ? z : z - nz0;
    src += (size_t)e * K * N;
    dst += (size_t)e * K * N;
    int n0 = blockIdx.x * 64, k0 = blockIdx.y * 64;
    int t = threadIdx.x;
    int lr = t >> 4;          // 0..15
    int lc = (t & 15) * 4;    // 0..60
#pragma unroll
    for (int p = 0; p < 4; ++p) {
        int kl = p * 16 + lr;
        float4 v = *(const float4*)(src + (size_t)(k0 + kl) * N + n0 + lc);
        tile[kl][lc + 0] = f2bf(v.x);
        tile[kl][lc + 1] = f2bf(v.y);
        tile[kl][lc + 2] = f2bf(v.z);
        tile[kl][lc + 3] = f2bf(v.w);
    }
    __syncthreads();
    int sn = t >> 3;          // 0..31
    int sk = (t & 7) * 8;     // 0..56
#pragma unroll
    for (int p = 0; p < 2; ++p) {
        int nl = p * 32 + sn;
        u16x8 o;
#pragma unroll
        for (int j = 0; j < 8; ++j) o[j] = tile[sk + j][nl];
        *(u16x8*)(dst + (size_t)(n0 + nl) * K + k0 + sk) = o;
    }
}

// ---------------- gating v3: 512 blocks, LDS-aggregated counts/sums ----------
__global__ __launch_bounds__(256) void gating_kernel(
    const float* __restrict__ h,
    const float* __restrict__ gw,
    float* __restrict__ route,
    int* __restrict__ sel01,
    float2* __restrict__ wpair,
    int* __restrict__ counts,
    float* __restrict__ sums,
    unsigned short* __restrict__ hb) {
    __shared__ int lcnt[8];
    __shared__ float lsum[8];
    const int tid = threadIdx.x;
    if (tid < 8) { lcnt[tid] = 0; lsum[tid] = 0.f; }
    __syncthreads();
    const int wid = tid >> 6, lane = tid & 63;

    for (int t0 = 0; t0 < B_TOK; t0 += 2048) {
        int t = t0 + blockIdx.x * 4 + wid;
        const float* hp = h + (size_t)t * DDIM + lane * 16;
        float4 hv[4];
#pragma unroll
        for (int p = 0; p < 4; ++p) hv[p] = ((const float4*)hp)[p];

        u16x8 o0, o1;
        o0[0] = f2bf(hv[0].x); o0[1] = f2bf(hv[0].y); o0[2] = f2bf(hv[0].z); o0[3] = f2bf(hv[0].w);
        o0[4] = f2bf(hv[1].x); o0[5] = f2bf(hv[1].y); o0[6] = f2bf(hv[1].z); o0[7] = f2bf(hv[1].w);
        o1[0] = f2bf(hv[2].x); o1[1] = f2bf(hv[2].y); o1[2] = f2bf(hv[2].z); o1[3] = f2bf(hv[2].w);
        o1[4] = f2bf(hv[3].x); o1[5] = f2bf(hv[3].y); o1[6] = f2bf(hv[3].z); o1[7] = f2bf(hv[3].w);
        unsigned short* hbp = hb + (size_t)t * DDIM + lane * 16;
        *(u16x8*)hbp = o0;
        *(u16x8*)(hbp + 8) = o1;

        const float4* gp4 = (const float4*)(gw + (size_t)lane * 16 * NEXP);
        float s[8] = {0, 0, 0, 0, 0, 0, 0, 0};
#pragma unroll
        for (int p = 0; p < 4; ++p) {
#pragma unroll
            for (int q = 0; q < 4; ++q) {
                int kk = p * 4 + q;
                float hvk = (q == 0) ? hv[p].x : (q == 1) ? hv[p].y : (q == 2) ? hv[p].z : hv[p].w;
                float4 a = gp4[kk * 2], b = gp4[kk * 2 + 1];
                s[0] += hvk * a.x; s[1] += hvk * a.y; s[2] += hvk * a.z; s[3] += hvk * a.w;
                s[4] += hvk * b.x; s[5] += hvk * b.y; s[6] += hvk * b.z; s[7] += hvk * b.w;
            }
        }
#pragma unroll
        for (int off = 32; off > 0; off >>= 1) {
#pragma unroll
            for (int e = 0; e < 8; ++e) s[e] += __shfl_down(s[e], off);
        }
        if (lane == 0) {
            float m0 = -1e30f; int i0 = 0;
#pragma unroll
            for (int e = 0; e < 8; ++e) if (s[e] > m0) { m0 = s[e]; i0 = e; }
            float m1 = -1e30f; int i1 = -1;
#pragma unroll
            for (int e = 0; e < 8; ++e) if (e != i0 && s[e] > m1) { m1 = s[e]; i1 = e; }
            float d = __expf(m1 - m0);
            float w0 = 1.f / (1.f + d);
            float w1 = d * w0;
#pragma unroll
            for (int e = 0; e < 8; ++e)
                route[(size_t)t * 8 + e] = (e == i0) ? w0 : ((e == i1) ? w1 : 0.f);
            sel01[t] = i0 | (i1 << 8);
            wpair[t] = make_float2(w0, w1);
            atomicAdd(&lcnt[i0], 1);
            atomicAdd(&lcnt[i1], 1);
            atomicAdd(&lsum[i0], w0);
            atomicAdd(&lsum[i1], w1);
        }
    }
    __syncthreads();
    if (tid < 8) {
        atomicAdd(&counts[tid], lcnt[tid]);
        atomicAdd(&sums[tid], lsum[tid]);
    }
}

// single block: per-expert 128-aligned slot offsets + tile table + lb_loss finalize
__global__ void setup_kernel(const int* __restrict__ counts,
                             const float* __restrict__ sums,
                             int* __restrict__ aoff,
                             int* __restrict__ tile_e,
                             int* __restrict__ tile_s0,
                             float* __restrict__ lb) {
    __shared__ int s_aoff[8], s_t0[9];
    if (threadIdx.x == 0) {
        int acc_slot = 0, acc_tile = 0;
        for (int e = 0; e < 8; ++e) {
            s_aoff[e] = acc_slot;
            s_t0[e] = acc_tile;
            int nt = (counts[e] + 127) >> 7;
            acc_slot += nt << 7;
            acc_tile += nt;
        }
        s_t0[8] = acc_tile;
        for (int e = 0; e < 8; ++e) aoff[e] = s_aoff[e];
        float acc = 0.f;
        for (int e = 0; e < 8; ++e) {
            float p = sums[e] / (float)B_TOK;
            acc += p * p;
        }
        lb[0] = 0.01f * acc;
    }
    __syncthreads();
    int t = threadIdx.x;
    if (t < CAP_TILES) {
        int e = -1, s0 = 0;
        for (int x = 0; x < 8; ++x)
            if (t >= s_t0[x] && t < s_t0[x + 1]) { e = x; s0 = s_aoff[x] + ((t - s_t0[x]) << 7); }
        tile_e[t] = e;
        tile_s0[t] = s0;
    }
}

// fill v2: per-block LDS ranks + one block-reservation atomic per expert.
__global__ __launch_bounds__(256) void fill_kernel(
    const int* __restrict__ sel01,
    const int* __restrict__ aoff,
    int* __restrict__ rank,
    int* __restrict__ idx,
    int2* __restrict__ tslot) {
    __shared__ int lcnt[8], lbase[8];
    const int tid = threadIdx.x;
    if (tid < 8) lcnt[tid] = 0;
    __syncthreads();
    int t = blockIdx.x * 256 + tid;
    int s = sel01[t];
    int e0 = s & 0xff, e1 = (s >> 8) & 0xff;
    int lr0 = atomicAdd(&lcnt[e0], 1);
    int lr1 = atomicAdd(&lcnt[e1], 1);
    __syncthreads();
    if (tid < 8) lbase[tid] = atomicAdd(&rank[tid], lcnt[tid]);
    __syncthreads();
    int sl0 = aoff[e0] + lbase[e0] + lr0;
    int sl1 = aoff[e1] + lbase[e1] + lr1;
    idx[sl0] = t;
    idx[sl1] = t;
    tslot[t] = make_int2(sl0, sl1);
}

// ---------------- GEMM1 8-phase (r15-verified: 231us, 0 bank conflicts) -------
__global__ __launch_bounds__(512, 2) void gemm1_8ph(
    const unsigned short* __restrict__ A,
    const unsigned short* __restrict__ Bg,
    const unsigned short* __restrict__ Bu,
    const int* __restrict__ tile_e,
    const int* __restrict__ tile_s0,
    const int* __restrict__ idx,
    unsigned short* __restrict__ act) {
    const int lin = blockIdx.x;
    const int swz = (lin & 7) * (NWG1 / 8) + (lin >> 3);
    const int tileId = swz % CAP_TILES;
    const int colBase = (swz / CAP_TILES) * 256;
    int e = tile_e[tileId];
    if (e < 0) return;
    const int slot0 = tile_s0[tileId];
    const unsigned short* Gp = Bg + (size_t)e * DDIM * INTER;
    const unsigned short* Up = Bu + (size_t)e * DDIM * INTER;

    __shared__ unsigned short lds[81920];   // 160 KiB

    const int t = threadIdx.x;
    const int w = t >> 6, lane = t & 63;
    const int wr = w >> 2, wc = w & 3;
    const int l15 = lane & 15;
    const int kb8 = (lane >> 4) * 8;
    const int t8 = t * 8;
    const int rowIdx = t >> 3;                                  // 0..63
    const int kus = ((t & 7) * 8) ^ (((t >> 3) & 7) << 3);      // swizzled src col

    const unsigned short* Ab0 = A + (size_t)idx[slot0 + rowIdx] * DDIM + kus;
    const unsigned short* Ab1 = A + (size_t)idx[slot0 + 64 + rowIdx] * DDIM + kus;
    const unsigned int gbase = (unsigned int)(colBase + rowIdx) * DDIM + kus;

    f32x4 accG[4][4], accU[4][4];
#pragma unroll
    for (int i = 0; i < 4; ++i)
#pragma unroll
        for (int jq = 0; jq < 4; ++jq) { accG[i][jq] = (f32x4)(0.f); accU[i][jq] = (f32x4)(0.f); }

#define STA(s, kt) { \
    gload_lds16(Ab0 + (kt) * 64, (void*)(lds + (s) * 40960 + t8)); \
    gload_lds16(Ab1 + (kt) * 64, (void*)(lds + (s) * 40960 + 4096 + t8)); }
#define STG(s, hh, kt) { \
    gload_lds16(Gp + gbase + (2 * (hh)) * 65536 + (kt) * 64,     (void*)(lds + (s) * 40960 + 8192 + (2 * (hh)) * 4096 + t8)); \
    gload_lds16(Gp + gbase + (2 * (hh) + 1) * 65536 + (kt) * 64, (void*)(lds + (s) * 40960 + 8192 + (2 * (hh) + 1) * 4096 + t8)); }
#define STU(s, hh, kt) { \
    gload_lds16(Up + gbase + (2 * (hh)) * 65536 + (kt) * 64,     (void*)(lds + (s) * 40960 + 24576 + (2 * (hh)) * 4096 + t8)); \
    gload_lds16(Up + gbase + (2 * (hh) + 1) * 65536 + (kt) * 64, (void*)(lds + (s) * 40960 + 24576 + (2 * (hh) + 1) * 4096 + t8)); }
#define DSA(s, kk) { _Pragma("unroll") for (int mf = 0; mf < 4; ++mf) { \
    int lr = wr * 64 + mf * 16 + l15; \
    a[mf] = *(const s16x8*)&lds[(s) * 40960 + lr * 64 + (((kk) * 32 + kb8) ^ ((lr & 7) << 3))]; } }
#define DSB(dst, s, off, kk) { _Pragma("unroll") for (int nf = 0; nf < 4; ++nf) { \
    int rr = wc * 64 + nf * 16 + l15; \
    dst[nf] = *(const s16x8*)&lds[(s) * 40960 + (off) + rr * 64 + (((kk) * 32 + kb8) ^ ((rr & 7) << 3))]; } }
#define MM(ACC, B) { _Pragma("unroll") for (int mf = 0; mf < 4; ++mf) \
    _Pragma("unroll") for (int nf = 0; nf < 4; ++nf) \
        ACC[mf][nf] = __builtin_amdgcn_mfma_f32_16x16x32_bf16(a[mf], B[nf], ACC[mf][nf], 0, 0, 0); }
#define PH_TAIL(ACC, B) \
    __builtin_amdgcn_s_barrier(); \
    asm volatile("s_waitcnt lgkmcnt(0)" ::: "memory"); \
    __builtin_amdgcn_sched_barrier(0); \
    __builtin_amdgcn_s_setprio(1); \
    MM(ACC, B); \
    __builtin_amdgcn_s_setprio(0); \
    __builtin_amdgcn_sched_barrier(0); \
    __builtin_amdgcn_s_barrier();

    // prologue: slot0 <- tile0 (10 loads), slot1 A+Gh0 <- tile1 (4 loads)
    STA(0, 0); STG(0, 0, 0); STG(0, 1, 0); STU(0, 0, 0); STU(0, 1, 0);
    STA(1, 1); STG(1, 0, 1);
    asm volatile("s_waitcnt vmcnt(8)" ::: "memory");
    __builtin_amdgcn_s_barrier();

    s16x8 a[4], bg[4], bu[4];
#pragma unroll 1
    for (int j = 0; j < 8; ++j) {   // DDIM/BK2/2 = 8 periods
        const bool nl = (j < 7);
        const int t1 = 2 * j + 1, t2 = 2 * j + 2, t3 = 2 * j + 3;
        // ph0: G kk0 (slot0); stage Gh1,Uh0 (slot1, tile t1)
        DSA(0, 0); DSB(bg, 0, 8192, 0);
        STG(1, 1, t1); STU(1, 0, t1);
        asm volatile("s_waitcnt vmcnt(8)" ::: "memory");
        PH_TAIL(accG, bg);
        // ph1: U kk0 (slot0); stage Uh1 (slot1, t1)
        DSB(bu, 0, 24576, 0);
        STU(1, 1, t1);
        PH_TAIL(accU, bu);
        // ph2: G kk1 (slot0)
        DSA(0, 1); DSB(bg, 0, 8192, 1);
        PH_TAIL(accG, bg);
        // ph3: U kk1 (slot0); stage A,Gh0 (slot0, t2)
        DSB(bu, 0, 24576, 1);
        if (nl) { STA(0, t2); STG(0, 0, t2); }
        if (nl) { asm volatile("s_waitcnt vmcnt(6)" ::: "memory"); }
        else    { asm volatile("s_waitcnt vmcnt(4)" ::: "memory"); }
        PH_TAIL(accU, bu);
        // ph4: G kk0 (slot1); stage Gh1,Uh0 (slot0, t2)
        DSA(1, 0); DSB(bg, 1, 8192, 0);
        if (nl) { STG(0, 1, t2); STU(0, 0, t2); }
        if (nl) { asm volatile("s_waitcnt vmcnt(8)" ::: "memory"); }
        else    { asm volatile("s_waitcnt vmcnt(0)" ::: "memory"); }
        PH_TAIL(accG, bg);
        // ph5: U kk0 (slot1); stage Uh1 (slot0, t2)
        DSB(bu, 1, 24576, 0);
        if (nl) { STU(0, 1, t2); }
        PH_TAIL(accU, bu);
        // ph6: G kk1 (slot1)
        DSA(1, 1); DSB(bg, 1, 8192, 1);
        PH_TAIL(accG, bg);
        // ph7: U kk1 (slot1); stage A,Gh0 (slot1, t3)
        DSB(bu, 1, 24576, 1);
        if (nl) { STA(1, t3); STG(1, 0, t3); }
        if (nl) { asm volatile("s_waitcnt vmcnt(6)" ::: "memory"); }
        PH_TAIL(accU, bu);
    }

#pragma unroll
    for (int mf = 0; mf < 4; ++mf)
#pragma unroll
        for (int nf = 0; nf < 4; ++nf)
#pragma unroll
            for (int jq = 0; jq < 4; ++jq) {
                int r = slot0 + wr * 64 + mf * 16 + (lane >> 4) * 4 + jq;
                int c = colBase + wc * 64 + nf * 16 + l15;
                float g = accG[mf][nf][jq], u = accU[mf][nf][jq];
                float sg = 1.f / (1.f + __expf(-g));
                act[(size_t)r * INTER + c] = f2bf(g * sg * u);
            }
#undef STA
#undef STG
#undef STU
#undef DSA
#undef DSB
#undef MM
#undef PH_TAIL
}

// ---------------- GEMM2 v4 + XCD-bijective swizzle; 4 blocks/CU ---------------
__global__ __launch_bounds__(256, 4) void gemm2_sparse_v4(
    const unsigned short* __restrict__ A,
    const unsigned short* __restrict__ Bd,
    const int* __restrict__ tile_e,
    const int* __restrict__ tile_s0,
    unsigned short* __restrict__ y) {
    const int lin = blockIdx.x;
    const int swz = (lin & 7) * (NWG2 / 8) + (lin >> 3);
    const int tileId = swz % CAP_TILES;
    const int colBase = (swz / CAP_TILES) * 128;
    int e = tile_e[tileId];
    if (e < 0) return;
    const int slot0 = tile_s0[tileId];
    Bd += (size_t)e * DDIM * INTER;

    __shared__ unsigned short sA[2][128 * 32];
    __shared__ unsigned short sB[2][128 * 32];
    const int tid = threadIdx.x, wid = tid >> 6, lane = tid & 63;
    const int wr = wid >> 1, wc = wid & 1;

    f32x4 acc[4][4];
#pragma unroll
    for (int i = 0; i < 4; ++i)
#pragma unroll
        for (int j = 0; j < 4; ++j) acc[i][j] = (f32x4)(0.f);

    const int c0 = wid, c1 = wid + 4;
    const int srow = lane >> 2;
    const int skoff = (lane & 3) * 8;
    const int rA = (lane & 15) * 32 + (lane >> 4) * 8;

    const size_t gA0 = (size_t)(slot0 + c0 * 16 + srow) * INTER + skoff;
    const size_t gA1 = (size_t)(slot0 + c1 * 16 + srow) * INTER + skoff;
    const size_t gB0 = (size_t)(colBase + c0 * 16 + srow) * INTER + skoff;
    const size_t gB1 = (size_t)(colBase + c1 * 16 + srow) * INTER + skoff;

    for (int k0 = 0; k0 < INTER; k0 += 64) {
#pragma unroll
        for (int kk = 0; kk < 2; ++kk) {
            int k = k0 + kk * 32;
            gload_lds16(A + gA0 + k, sA[kk] + c0 * 512);
            gload_lds16(A + gA1 + k, sA[kk] + c1 * 512);
            gload_lds16(Bd + gB0 + k, sB[kk] + c0 * 512);
            gload_lds16(Bd + gB1 + k, sB[kk] + c1 * 512);
        }
        asm volatile("s_waitcnt vmcnt(0)" ::: "memory");
        __syncthreads();

#pragma unroll
        for (int kk = 0; kk < 2; ++kk) {
            s16x8 a[4], b[4];
#pragma unroll
            for (int mf = 0; mf < 4; ++mf)
                a[mf] = *(const s16x8*)&sA[kk][(wr * 64 + mf * 16) * 32 + rA];
#pragma unroll
            for (int nf = 0; nf < 4; ++nf)
                b[nf] = *(const s16x8*)&sB[kk][(wc * 64 + nf * 16) * 32 + rA];
#pragma unroll
            for (int mf = 0; mf < 4; ++mf)
#pragma unroll
                for (int nf = 0; nf < 4; ++nf)
                    acc[mf][nf] = __builtin_amdgcn_mfma_f32_16x16x32_bf16(a[mf], b[nf], acc[mf][nf], 0, 0, 0);
        }
        __syncthreads();
    }

#pragma unroll
    for (int mf = 0; mf < 4; ++mf)
#pragma unroll
        for (int j = 0; j < 4; ++j) {
            int slot = slot0 + wr * 64 + mf * 16 + (lane >> 4) * 4 + j;
#pragma unroll
            for (int nf = 0; nf < 4; ++nf) {
                int c = colBase + wc * 64 + nf * 16 + (lane & 15);
                y[(size_t)slot * DDIM + c] = f2bf(acc[mf][nf][j]);
            }
        }
}

// out[t][c] = w0 * y[sl0][c] + w1 * y[sl1][c]; y is bf16, out f32
__global__ __launch_bounds__(256) void combine_kernel(
    const unsigned short* __restrict__ y,
    const int2* __restrict__ tslot,
    const float2* __restrict__ wpair,
    float* __restrict__ out) {
    int gid = blockIdx.x * 256 + threadIdx.x;  // 0 .. 8192*128-1
    int tok = gid >> 7;
    int c8 = (gid & 127) * 8;
    int2 ts = tslot[tok];
    float2 w = wpair[tok];
    u16x8 a = *(const u16x8*)(y + (size_t)ts.x * DDIM + c8);
    u16x8 b = *(const u16x8*)(y + (size_t)ts.y * DDIM + c8);
    float4 r0, r1;
    r0.x = w.x * bf2f(a[0]) + w.y * bf2f(b[0]);
    r0.y = w.x * bf2f(a[1]) + w.y * bf2f(b[1]);
    r0.z = w.x * bf2f(a[2]) + w.y * bf2f(b[2]);
    r0.w = w.x * bf2f(a[3]) + w.y * bf2f(b[3]);
    r1.x = w.x * bf2f(a[4]) + w.y * bf2f(b[4]);
    r1.y = w.x * bf2f(a[5]) + w.y * bf2f(b[5]);
    r1.z = w.x * bf2f(a[6]) + w.y * bf2f(b[6]);
    r1.w = w.x * bf2f(a[7]) + w.y * bf2f(b[7]);
    float* op = out + (size_t)tok * DDIM + c8;
    *(float4*)op = r0;
    *(float4*)(op + 4) = r1;
}

// ---------------- host ----------------

extern "C" void kernel_launch(void* const* d_in, const int* in_sizes, int n_in,
                              void* d_out, int out_size, void* d_ws, size_t ws_size,
                              hipStream_t stream) {
    const float* h = (const float*)d_in[0];
    const float* gate_w = (const float*)d_in[1];
    const float* wg = (const float*)d_in[2];
    const float* wu = (const float*)d_in[3];
    const float* wd = (const float*)d_in[4];

    float* out = (float*)d_out;                       // results: 8192*1024
    float* lb = out + (size_t)B_TOK * DDIM;           // 1
    float* route = lb + 1;                            // 8192*8

    const size_t SZ_META = 1 << 20;                           // 1 MiB
    const size_t SZ_HB = (size_t)B_TOK * DDIM * 2;            // 16,777,216
    const size_t SZ_W = (size_t)NEXP * DDIM * INTER * 2;      // 46,137,344 per tensor
    const size_t SZ_ACT = (size_t)CAP_SLOTS * INTER * 2;      // 98,041,856
    const size_t NEED = SZ_META + SZ_HB + 2 * SZ_W + SZ_ACT;  // ~198.5 MiB
    if (ws_size < NEED) {
        fprintf(stderr, "kernel_launch: ws too small: %zu < %zu\n", ws_size, NEED);
        return;
    }
    char* ws = (char*)d_ws;
    // meta layout (within first 1 MiB)
    int* counts = (int*)(ws + 0);            // 8
    int* rank = (int*)(ws + 32);             // 8
    int* aoff = (int*)(ws + 64);             // 8
    float* sums = (float*)(ws + 96);         // 8
    int* tile_e = (int*)(ws + 128);          // 136
    int* tile_s0 = (int*)(ws + 1024);        // 136
    int* sel01 = (int*)(ws + 2048);          // 8192
    float2* wpair = (float2*)(ws + 34816);   // 8192
    int* idx = (int*)(ws + 100352);          // 17408
    int2* tslot = (int2*)(ws + 262144);      // 8192 int2 = 64KB

    unsigned short* hb = (unsigned short*)(ws + SZ_META);
    unsigned short* wgT = (unsigned short*)(ws + SZ_META + SZ_HB);
    unsigned short* wuT = (unsigned short*)(ws + SZ_META + SZ_HB + SZ_W);
    unsigned short* act = (unsigned short*)(ws + SZ_META + SZ_HB + 2 * SZ_W);
    unsigned short* wdT = wgT;                               // reuse wgT space AFTER gemm1
    unsigned short* y = wuT;                                 // reuse wuT space AFTER gemm1 (35.6MB < 44MB)

    hipMemsetAsync(ws, 0, SZ_META, stream);

    // fused wg+wu transpose: z in [0,16)
    transpose_convert_v2<<<dim3(INTER / 64, DDIM / 64, 2 * NEXP), 256, 0, stream>>>(
        wg, wu, wgT, wuT, DDIM, INTER, NEXP);

    gating_kernel<<<512, 256, 0, stream>>>(h, gate_w, route, sel01, wpair, counts, sums, hb);
    setup_kernel<<<1, 256, 0, stream>>>(counts, sums, aoff, tile_e, tile_s0, lb);
    fill_kernel<<<B_TOK / 256, 256, 0, stream>>>(sel01, aoff, rank, idx, tslot);

    gemm1_8ph<<<NWG1, 512, 0, stream>>>(hb, wgT, wuT, tile_e, tile_s0, idx, act);

    // now wgT/wuT are dead: transpose wd into wgT's space; y reuses wuT's space
    transpose_convert_v2<<<dim3(DDIM / 64, INTER / 64, NEXP), 256, 0, stream>>>(
        wd, wd, wdT, wdT, INTER, DDIM, NEXP);

    gemm2_sparse_v4<<<NWG2, 256, 0, stream>>>(act, wdT, tile_e, tile_s0, y);

    combine_kernel<<<(B_TOK * 128) / 256, 256, 0, stream>>>(y, tslot, wpair, out);
}